// Round 18
// baseline (695.162 us; speedup 1.0000x reference)
//
#include <hip/hip_runtime.h>
#include <hip/hip_bf16.h>
#include <math.h>

// Round 18: expert GEMMs (non-split) switched to dbuf + global_load_lds
// pipeline (m151 recipe: 874 vs 646 TF at this exact tile). 64KB LDS keeps
// 2 blocks/CU; prefetch regs eliminated. Split-3 GEMMs (QKV+RoPE, proj)
// unchanged from r17 (652us best). Swizzle pairing = r8-verified scheme.
// B=2 T=2048 D=1024 NH=16 HD=64 HALF=32 NEXP=8 TOPK=2 CAP=1024 FF=4096

#define TT 2048
#define NTOK 4096

typedef __attribute__((ext_vector_type(8))) short bf16x8;
typedef __attribute__((ext_vector_type(4))) float f32x4;
typedef __attribute__((ext_vector_type(16))) float f32x16;

static __device__ __forceinline__ ushort f2bf(float f) {
  union { float f; unsigned u; } v; v.f = f;
  unsigned r = v.u + 0x7FFFu + ((v.u >> 16) & 1u);
  return (ushort)(r >> 16);
}
static __device__ __forceinline__ float bf2f(ushort h) {
  union { unsigned u; float f; } v; v.u = ((unsigned)h) << 16; return v.f;
}
static __device__ __forceinline__ unsigned cvt_pk_bf16(float lo, float hi) {
  unsigned r;
  asm("v_cvt_pk_bf16_f32 %0, %1, %2" : "=v"(r) : "v"(lo), "v"(hi));
  return r;
}
static __device__ __forceinline__ void plane_swap(unsigned& a, unsigned& b) {
  asm("v_permlane32_swap_b32 %0, %1" : "+v"(a), "+v"(b));
}
static __device__ __forceinline__ float fexp2(float x) {
  float r;
  asm("v_exp_f32 %0, %1" : "=v"(r) : "v"(x));
  return r;
}
static __device__ __forceinline__ void gload16(const void* g, void* l) {
  __builtin_amdgcn_global_load_lds(
      (const __attribute__((address_space(1))) void*)g,
      (__attribute__((address_space(3))) void*)l, 16, 0, 0);
}

// ---------------------------------------------------------------- LayerNorm (+ bf16 split; GATE: fused router)
template<bool GATE>
__global__ __launch_bounds__(256)
void ln_kernel(const float* __restrict__ x, const float* __restrict__ g,
               const float* __restrict__ b, ushort* __restrict__ oh,
               ushort* __restrict__ ol, const float* __restrict__ Wg,
               int* __restrict__ te, float* __restrict__ tv, int* __restrict__ inv) {
  __shared__ float srow[1024];
  int row = blockIdx.x, tid = threadIdx.x;
  const float4* xr = (const float4*)(x + (size_t)row * 1024);
  float4 v = xr[tid];
  float s = v.x + v.y + v.z + v.w;
  #pragma unroll
  for (int off = 1; off < 64; off <<= 1) s += __shfl_xor(s, off);
  __shared__ float red1[4], red2[4];
  if ((tid & 63) == 0) red1[tid >> 6] = s;
  __syncthreads();
  float mu = (red1[0] + red1[1] + red1[2] + red1[3]) * (1.0f / 1024.0f);
  float dx = v.x - mu, dy = v.y - mu, dz = v.z - mu, dw = v.w - mu;
  float ss = dx*dx + dy*dy + dz*dz + dw*dw;
  #pragma unroll
  for (int off = 1; off < 64; off <<= 1) ss += __shfl_xor(ss, off);
  if ((tid & 63) == 0) red2[tid >> 6] = ss;
  __syncthreads();
  float var = (red2[0] + red2[1] + red2[2] + red2[3]) * (1.0f / 1024.0f);
  float inv_ = 1.0f / sqrtf(var + 1e-5f);
  float4 g4 = ((const float4*)g)[tid];
  float4 b4 = ((const float4*)b)[tid];
  float4 o4;
  o4.x = dx * inv_ * g4.x + b4.x;
  o4.y = dy * inv_ * g4.y + b4.y;
  o4.z = dz * inv_ * g4.z + b4.z;
  o4.w = dw * inv_ * g4.w + b4.w;
  size_t base = (size_t)row * 1024 + tid * 4;
  ushort h0 = f2bf(o4.x), h1 = f2bf(o4.y), h2 = f2bf(o4.z), h3 = f2bf(o4.w);
  ushort4 hh = {h0, h1, h2, h3};
  *(ushort4*)(oh + base) = hh;
  ushort4 ll = {f2bf(o4.x - bf2f(h0)), f2bf(o4.y - bf2f(h1)),
                f2bf(o4.z - bf2f(h2)), f2bf(o4.w - bf2f(h3))};
  *(ushort4*)(ol + base) = ll;
  if constexpr (GATE) {
    *(float4*)&srow[tid * 4] = o4;
    __syncthreads();
    float acc[8] = {};
    for (int i = tid; i < 1024; i += 256) {
      float xv = srow[i];
      const float4* wr = (const float4*)&Wg[i * 8];
      float4 w0 = wr[0], w1 = wr[1];
      acc[0] += xv * w0.x; acc[1] += xv * w0.y; acc[2] += xv * w0.z; acc[3] += xv * w0.w;
      acc[4] += xv * w1.x; acc[5] += xv * w1.y; acc[6] += xv * w1.z; acc[7] += xv * w1.w;
    }
    #pragma unroll
    for (int off = 1; off < 64; off <<= 1)
      #pragma unroll
      for (int qq = 0; qq < 8; ++qq) acc[qq] += __shfl_xor(acc[qq], off);
    __shared__ float red[4][8];
    if ((tid & 63) == 0)
      #pragma unroll
      for (int qq = 0; qq < 8; ++qq) red[tid >> 6][qq] = acc[qq];
    __syncthreads();
    if (tid == 0) {
      float gg[8];
      #pragma unroll
      for (int qq = 0; qq < 8; ++qq) gg[qq] = red[0][qq] + red[1][qq] + red[2][qq] + red[3][qq];
      float mx = gg[0];
      #pragma unroll
      for (int qq = 1; qq < 8; ++qq) mx = fmaxf(mx, gg[qq]);
      float sum = 0.0f;
      #pragma unroll
      for (int qq = 0; qq < 8; ++qq) { gg[qq] = expf(gg[qq] - mx); sum += gg[qq]; }
      float inv_s = 1.0f / sum;
      #pragma unroll
      for (int qq = 0; qq < 8; ++qq) gg[qq] *= inv_s;
      int e1 = 0; float v1 = gg[0];
      for (int qq = 1; qq < 8; ++qq) if (gg[qq] > v1) { v1 = gg[qq]; e1 = qq; }
      int e2 = -1; float v2 = -1.0f;
      for (int qq = 0; qq < 8; ++qq) { if (qq == e1) continue; if (gg[qq] > v2) { v2 = gg[qq]; e2 = qq; } }
      te[row * 2] = e1; te[row * 2 + 1] = e2;
      tv[row * 2] = v1; tv[row * 2 + 1] = v2;
      inv[row * 2] = -1; inv[row * 2 + 1] = -1;
    }
  }
}

// ---------------------------------------------------------------- RoPE tables (f64)
__global__ void sincos_kernel(float* __restrict__ st, float* __restrict__ ct) {
  int t = blockIdx.x, j = threadIdx.x;
  double invf = pow(10000.0, -((double)(2 * j)) / 64.0);
  double ang = (double)t * invf;
  st[t * 32 + j] = (float)sin(ang);
  ct[t * 32 + j] = (float)cos(ang);
}

// ---------------------------------------------------------------- V^T prep: [b,t,h*64] f32 -> [b,h,64,t] bf16 hi/lo
__global__ __launch_bounds__(256)
void vtprep_kernel(const float* __restrict__ vout, ushort* __restrict__ Vth,
                   ushort* __restrict__ Vtl) {
  __shared__ float tile[64][65];
  int t0 = blockIdx.x * 64, h = blockIdx.y, b = blockIdx.z;
  int tid = threadIdx.x;
  #pragma unroll
  for (int l = 0; l < 4; ++l) {
    int idx = l * 256 + tid;
    int r = idx >> 4, c4 = (idx & 15) * 4;
    *(float4*)&tile[r][c4] = *(const float4*)&vout[((size_t)(b * TT + t0 + r)) * 1024 + h * 64 + c4];
  }
  __syncthreads();
  int d = tid >> 2, ts = (tid & 3) * 16;
  union { bf16x8 v; ushort u[8]; } H0, H1, L0, L1;
  #pragma unroll
  for (int i = 0; i < 8; ++i) {
    float v0 = tile[ts + i][d];
    ushort hb0 = f2bf(v0);
    H0.u[i] = hb0; L0.u[i] = f2bf(v0 - bf2f(hb0));
    float v1 = tile[ts + 8 + i][d];
    ushort hb1 = f2bf(v1);
    H1.u[i] = hb1; L1.u[i] = f2bf(v1 - bf2f(hb1));
  }
  size_t basep = ((size_t)(b * 16 + h) * 64 + d) * TT + t0 + ts;
  *(bf16x8*)(Vth + basep) = H0.v;  *(bf16x8*)(Vth + basep + 8) = H1.v;
  *(bf16x8*)(Vtl + basep) = L0.v;  *(bf16x8*)(Vtl + basep + 8) = L1.v;
}

// ---------------------------------------------------------------- flash v11 (unchanged)
__global__ __launch_bounds__(256)
void flash11_kernel(const ushort* __restrict__ Qh, const ushort* __restrict__ Ql,
                    const ushort* __restrict__ Kh, const ushort* __restrict__ Kl,
                    const ushort* __restrict__ Vth, const ushort* __restrict__ Vtl,
                    float* __restrict__ Opart, float* __restrict__ Mpart,
                    float* __restrict__ Lpart) {
  int lin = blockIdx.x;                     // 1280
  int xcd = lin & 7, s = lin >> 3;
  int bh = xcd + 8 * (s / 40);
  int j = 39 - (s % 40);
  int qt, kc;
  if (j < 4)       { qt = j;                    kc = 0; }
  else if (j < 12) { qt = 4 + ((j - 4) >> 1);   kc = (j - 4) & 1; }
  else if (j < 24) { qt = 8 + (j - 12) / 3;     kc = (j - 12) % 3; }
  else             { qt = 12 + ((j - 24) >> 2); kc = (j - 24) & 3; }
  int slot = bh * 40 + j;
  int h = bh & 15, b = bh >> 4;
  int tid = threadIdx.x;
  int w = tid >> 6, lane = tid & 63;
  int q = lane & 31, LH = lane >> 5;
  size_t bT = (size_t)b * TT;
  int qglob0 = qt * 128 + w * 32;
  int qg = qglob0 + q;
  bf16x8 qH[4], qL[4];
  {
    const ushort* qph = Qh + (bT + qg) * 1024 + h * 64 + LH * 8;
    const ushort* qpl = Ql + (bT + qg) * 1024 + h * 64 + LH * 8;
    #pragma unroll
    for (int dblk = 0; dblk < 4; ++dblk) {
      qH[dblk] = *(const bf16x8*)(qph + dblk * 16);
      qL[dblk] = *(const bf16x8*)(qpl + dblk * 16);
    }
  }
  const ushort* Kbh = Kh + (size_t)bh * TT * 64;
  const ushort* Kbl = Kl + (size_t)bh * TT * 64;
  const ushort* Vbh = Vth + (size_t)bh * 64 * TT;
  const ushort* Vbl = Vtl + (size_t)bh * 64 * TT;
  f32x16 accO0 = {}, accO1 = {};
  float m = -3.402823466e38f, lsum = 0.0f;
  int kvlo = kc * 512;
  int kvhi = min(kvlo + 512, qglob0 + 32);

  auto loadK = [&](bf16x8 (&kH)[4], bf16x8 (&kL)[4], int kv0) {
    const ushort* kbh = Kbh + (size_t)(kv0 + q) * 64 + LH * 8;
    const ushort* kbl = Kbl + (size_t)(kv0 + q) * 64 + LH * 8;
    #pragma unroll
    for (int dblk = 0; dblk < 4; ++dblk) {
      kH[dblk] = *(const bf16x8*)(kbh + dblk * 16);
      kL[dblk] = *(const bf16x8*)(kbl + dblk * 16);
    }
  };

  auto tile = [&](bf16x8 (&kH)[4], bf16x8 (&kL)[4],
                  bf16x8 (&kHn)[4], bf16x8 (&kLn)[4], int kv0, bool pf) {
    bf16x8 vAH[2][2], vAL[2][2];
    #pragma unroll
    for (int dblk = 0; dblk < 2; ++dblk)
      #pragma unroll
      for (int s2 = 0; s2 < 2; ++s2) {
        size_t ad = (size_t)(dblk * 32 + q) * TT + kv0 + s2 * 16 + LH * 8;
        vAH[dblk][s2] = *(const bf16x8*)(Vbh + ad);
        vAL[dblk][s2] = *(const bf16x8*)(Vbl + ad);
      }
    f32x16 sa = {}, sb = {};
    __builtin_amdgcn_s_setprio(1);
    sa = __builtin_amdgcn_mfma_f32_32x32x16_bf16(kH[0], qH[0], sa, 0, 0, 0);
    sb = __builtin_amdgcn_mfma_f32_32x32x16_bf16(kH[2], qH[2], sb, 0, 0, 0);
    sa = __builtin_amdgcn_mfma_f32_32x32x16_bf16(kH[1], qH[1], sa, 0, 0, 0);
    sb = __builtin_amdgcn_mfma_f32_32x32x16_bf16(kH[3], qH[3], sb, 0, 0, 0);
    sa = __builtin_amdgcn_mfma_f32_32x32x16_bf16(kH[0], qL[0], sa, 0, 0, 0);
    sb = __builtin_amdgcn_mfma_f32_32x32x16_bf16(kH[2], qL[2], sb, 0, 0, 0);
    sa = __builtin_amdgcn_mfma_f32_32x32x16_bf16(kH[1], qL[1], sa, 0, 0, 0);
    sb = __builtin_amdgcn_mfma_f32_32x32x16_bf16(kH[3], qL[3], sb, 0, 0, 0);
    sa = __builtin_amdgcn_mfma_f32_32x32x16_bf16(kL[0], qH[0], sa, 0, 0, 0);
    sb = __builtin_amdgcn_mfma_f32_32x32x16_bf16(kL[2], qH[2], sb, 0, 0, 0);
    sa = __builtin_amdgcn_mfma_f32_32x32x16_bf16(kL[1], qH[1], sa, 0, 0, 0);
    sb = __builtin_amdgcn_mfma_f32_32x32x16_bf16(kL[3], qH[3], sb, 0, 0, 0);
    __builtin_amdgcn_s_setprio(0);
    if (pf) loadK(kHn, kLn, kv0 + 32);
    float p[16];
    float pmax = -3.402823466e38f;
    if (kv0 + 31 > qglob0) {
      #pragma unroll
      for (int r = 0; r < 16; ++r) {
        int kvg = kv0 + (r & 3) + 8 * (r >> 2) + 4 * LH;
        float sv = (kvg <= qg) ? (sa[r] + sb[r]) : -3.402823466e38f;
        p[r] = sv; pmax = fmaxf(pmax, sv);
      }
    } else {
      #pragma unroll
      for (int r = 0; r < 16; ++r) {
        float sv = sa[r] + sb[r];
        p[r] = sv; pmax = fmaxf(pmax, sv);
      }
    }
    pmax = fmaxf(pmax, __shfl_xor(pmax, 32));
    float mnew = fmaxf(m, pmax);
    float fsc = fexp2(m - mnew);
    float psum = 0.0f;
    #pragma unroll
    for (int r = 0; r < 16; ++r) { p[r] = fexp2(p[r] - mnew); psum += p[r]; }
    psum += __shfl_xor(psum, 32);
    lsum = lsum * fsc + psum;
    m = mnew;
    #pragma unroll
    for (int r = 0; r < 16; ++r) { accO0[r] *= fsc; accO1[r] *= fsc; }
    bf16x8 pHf[2], pLf[2];
    #pragma unroll
    for (int s2 = 0; s2 < 2; ++s2) {
      int s8 = s2 * 8;
      unsigned a  = cvt_pk_bf16(p[s8 + 0], p[s8 + 1]);
      unsigned bw = cvt_pk_bf16(p[s8 + 2], p[s8 + 3]);
      unsigned c  = cvt_pk_bf16(p[s8 + 4], p[s8 + 5]);
      unsigned d  = cvt_pk_bf16(p[s8 + 6], p[s8 + 7]);
      float l0 = p[s8 + 0] - __uint_as_float(a << 16);
      float l1 = p[s8 + 1] - __uint_as_float(a & 0xFFFF0000u);
      float l2 = p[s8 + 2] - __uint_as_float(bw << 16);
      float l3 = p[s8 + 3] - __uint_as_float(bw & 0xFFFF0000u);
      float l4 = p[s8 + 4] - __uint_as_float(c << 16);
      float l5 = p[s8 + 5] - __uint_as_float(c & 0xFFFF0000u);
      float l6 = p[s8 + 6] - __uint_as_float(d << 16);
      float l7 = p[s8 + 7] - __uint_as_float(d & 0xFFFF0000u);
      unsigned al = cvt_pk_bf16(l0, l1);
      unsigned bl = cvt_pk_bf16(l2, l3);
      unsigned cl = cvt_pk_bf16(l4, l5);
      unsigned dl = cvt_pk_bf16(l6, l7);
      plane_swap(a, c); plane_swap(bw, d);
      plane_swap(al, cl); plane_swap(bl, dl);
      union { unsigned w[4]; bf16x8 v; } PH, PL;
      PH.w[0] = a;  PH.w[1] = bw; PH.w[2] = c;  PH.w[3] = d;
      PL.w[0] = al; PL.w[1] = bl; PL.w[2] = cl; PL.w[3] = dl;
      pHf[s2] = PH.v; pLf[s2] = PL.v;
    }
    __builtin_amdgcn_s_setprio(1);
    #pragma unroll
    for (int s2 = 0; s2 < 2; ++s2) {
      accO0 = __builtin_amdgcn_mfma_f32_32x32x16_bf16(vAH[0][s2], pHf[s2], accO0, 0, 0, 0);
      accO1 = __builtin_amdgcn_mfma_f32_32x32x16_bf16(vAH[1][s2], pHf[s2], accO1, 0, 0, 0);
      accO0 = __builtin_amdgcn_mfma_f32_32x32x16_bf16(vAH[0][s2], pLf[s2], accO0, 0, 0, 0);
      accO1 = __builtin_amdgcn_mfma_f32_32x32x16_bf16(vAH[1][s2], pLf[s2], accO1, 0, 0, 0);
      accO0 = __builtin_amdgcn_mfma_f32_32x32x16_bf16(vAL[0][s2], pHf[s2], accO0, 0, 0, 0);
      accO1 = __builtin_amdgcn_mfma_f32_32x32x16_bf16(vAL[1][s2], pHf[s2], accO1, 0, 0, 0);
    }
    __builtin_amdgcn_s_setprio(0);
  };

  bf16x8 kA[4], kB[4], kC[4], kD[4];
  loadK(kA, kB, kvlo);
  for (int kv0 = kvlo; kv0 < kvhi; kv0 += 64) {
    tile(kA, kB, kC, kD, kv0, kv0 + 32 < kvhi);
    if (kv0 + 32 < kvhi)
      tile(kC, kD, kA, kB, kv0 + 32, kv0 + 64 < kvhi);
  }

  if (LH == 0) {
    Mpart[slot * 128 + w * 32 + q] = m;      // log2 domain
    Lpart[slot * 128 + w * 32 + q] = lsum;
  }
  float* Ob = Opart + (size_t)slot * 8192 + (w * 32 + q) * 64;
  #pragma unroll
  for (int g2 = 0; g2 < 4; ++g2) {
    float4 v0 = {accO0[g2 * 4 + 0], accO0[g2 * 4 + 1], accO0[g2 * 4 + 2], accO0[g2 * 4 + 3]};
    *(float4*)(Ob + 8 * g2 + 4 * LH) = v0;
    float4 v1 = {accO1[g2 * 4 + 0], accO1[g2 * 4 + 1], accO1[g2 * 4 + 2], accO1[g2 * 4 + 3]};
    *(float4*)(Ob + 32 + 8 * g2 + 4 * LH) = v1;
  }
}

// ---------------------------------------------------------------- merge partials (exp2) -> bf16 hi/lo split
__global__ __launch_bounds__(256)
void fmerge2_kernel(const float* __restrict__ Opart, const float* __restrict__ Mpart,
                    const float* __restrict__ Lpart, ushort* __restrict__ oh,
                    ushort* __restrict__ ol) {
  int qt = blockIdx.x, bh = blockIdx.y;
  int h = bh & 15, b = bh >> 4;
  int g = qt >> 2;
  int nc = g + 1;
  int off = 2 * g * (g + 1) + (qt & 3) * (g + 1);
  int slot0 = bh * 40 + off;
  int tid = threadIdx.x;
  int q = tid & 127, dh = tid >> 7;
  float mg = -3.402823466e38f;
  for (int c = 0; c < nc; ++c) mg = fmaxf(mg, Mpart[(slot0 + c) * 128 + q]);
  float lg = 0.0f;
  float4 acc[8] = {};
  for (int c = 0; c < nc; ++c) {
    float sc = fexp2(Mpart[(slot0 + c) * 128 + q] - mg);
    lg += sc * Lpart[(slot0 + c) * 128 + q];
    const float4* op = (const float4*)(Opart + (size_t)(slot0 + c) * 8192 + q * 64 + dh * 32);
    #pragma unroll
    for (int i = 0; i < 8; ++i) {
      float4 v = op[i];
      acc[i].x += sc * v.x; acc[i].y += sc * v.y;
      acc[i].z += sc * v.z; acc[i].w += sc * v.w;
    }
  }
  float inv = 1.0f / lg;
  size_t obase = ((size_t)(b * TT + qt * 128 + q)) * 1024 + h * 64 + dh * 32;
  #pragma unroll
  for (int i = 0; i < 8; ++i) {
    float4 v = {acc[i].x * inv, acc[i].y * inv, acc[i].z * inv, acc[i].w * inv};
    ushort h0 = f2bf(v.x), h1 = f2bf(v.y), h2 = f2bf(v.z), h3 = f2bf(v.w);
    ushort4 hh = {h0, h1, h2, h3};
    *(ushort4*)(oh + obase + i * 4) = hh;
    ushort4 ll = {f2bf(v.x - bf2f(h0)), f2bf(v.y - bf2f(h1)),
                  f2bf(v.z - bf2f(h2)), f2bf(v.w - bf2f(h3))};
    *(ushort4*)(ol + obase + i * 4) = ll;
  }
}

// ---------------------------------------------------------------- transpose + bf16 convert (+lo split, small weights)
template<bool LO>
__global__ void tconv_kernel(const float* __restrict__ in, ushort* __restrict__ oh,
                             ushort* __restrict__ ol, int K, int N) {
  __shared__ float t[32][33];
  int z = blockIdx.z;
  const float* ip = in + (size_t)z * K * N;
  ushort* ohp = oh + (size_t)z * K * N;
  ushort* olp = LO ? (ol + (size_t)z * K * N) : nullptr;
  int n0 = blockIdx.x * 32, k0 = blockIdx.y * 32;
  int tx = threadIdx.x, ty = threadIdx.y;
  #pragma unroll
  for (int i = 0; i < 4; ++i)
    t[ty + 8 * i][tx] = ip[(size_t)(k0 + ty + 8 * i) * N + n0 + tx];
  __syncthreads();
  #pragma unroll
  for (int i = 0; i < 4; ++i) {
    float v = t[tx][ty + 8 * i];
    size_t off = (size_t)(n0 + ty + 8 * i) * K + k0 + tx;
    ushort hb = f2bf(v);
    ohp[off] = hb;
    if (LO) olp[off] = f2bf(v - bf2f(hb));
  }
}

// ---------------------------------------------------------------- tconv4: vectorized transpose+convert (W1/W2)
__global__ __launch_bounds__(256)
void tconv4_kernel(const float* __restrict__ in, ushort* __restrict__ out,
                   int K, int N) {
  __shared__ float t[64][68];
  int z = blockIdx.z;
  const float* ip = in + (size_t)z * K * N;
  ushort* op = out + (size_t)z * K * N;
  int n0 = blockIdx.x * 64, k0 = blockIdx.y * 64;
  int tid = threadIdx.x;
  int r = tid >> 4, c4 = (tid & 15) * 4;
  #pragma unroll
  for (int i = 0; i < 4; ++i)
    *(float4*)&t[r + 16 * i][c4] = *(const float4*)&ip[(size_t)(k0 + r + 16 * i) * N + n0 + c4];
  __syncthreads();
  int n = tid >> 2, kb = (tid & 3) * 16;
  union { ushort u[16]; ushort4 v[4]; } o;
  #pragma unroll
  for (int i = 0; i < 16; ++i) o.u[i] = f2bf(t[kb + i][n]);
  size_t ob = (size_t)(n0 + n) * K + k0 + kb;
  #pragma unroll
  for (int i = 0; i < 4; ++i) *(ushort4*)&op[ob + 4 * i] = o.v[i];
}

// ---------------------------------------------------------------- MFMA GEMM, split-3 (QKV+RoPE, proj) — unchanged r17
#define LOAD_STEP(tt) do {                                                     \
    int kk = (tt) << 6;                                                        \
    _Pragma("unroll")                                                          \
    for (int q = 0; q < 4; ++q) {                                              \
      int rr = r0 + 32 * q;                                                    \
      int clog = cph ^ (rr & 7);                                               \
      raH[q] = *(const bf16x8*)(AhB + (size_t)garow[q] * K + kk + clog * 8);   \
      rbH[q] = *(const bf16x8*)(BhB + (size_t)(bn + rr) * K + kk + clog * 8);  \
      raL[q] = *(const bf16x8*)(AlB + (size_t)garow[q] * K + kk + clog * 8);   \
      rbL[q] = *(const bf16x8*)(BlB + (size_t)(bn + rr) * K + kk + clog * 8);  \
    }                                                                          \
  } while (0)

template<int EPI>
__global__ __launch_bounds__(256, 2)
void mgemm(const ushort* __restrict__ Ah, const ushort* __restrict__ Al,
           const ushort* __restrict__ Bh, const ushort* __restrict__ Bl,
           void* __restrict__ Cv, const float* __restrict__ extra, int N, int K,
           const float* __restrict__ st, const float* __restrict__ ct,
           float* __restrict__ kout, float* __restrict__ vout,
           ushort* __restrict__ Kh, ushort* __restrict__ Kl,
           ushort* __restrict__ Qh, ushort* __restrict__ Ql) {
  __shared__ ushort As[2 * 128 * 64];
  __shared__ ushort Bs[2 * 128 * 64];
  ushort* AsH = As;  ushort* AsL = As + 128 * 64;
  ushort* BsH = Bs;  ushort* BsL = Bs + 128 * 64;
  const ushort* AhB = Ah;
  const ushort* AlB = Al;
  const ushort* BhB = Bh;
  const ushort* BlB = Bl;
  int bx = blockIdx.x, by = blockIdx.y;
  {
    int nwg = gridDim.x * gridDim.y;
    if ((nwg & 7) == 0) {
      int lid = bx + by * gridDim.x;
      int cpx = nwg >> 3;
      int wgid = (lid & 7) * cpx + (lid >> 3);
      bx = wgid % gridDim.x;
      by = wgid / gridDim.x;
    }
  }
  int bm = by * 128, bn = bx * 128;
  int tid = threadIdx.x;
  int r0 = tid >> 3, cph = tid & 7;
  int garow[4];
  #pragma unroll
  for (int q = 0; q < 4; ++q) garow[q] = bm + r0 + 32 * q;
  int kSteps = K >> 6;
  int wid = tid >> 6, lane = tid & 63;
  int wm = wid >> 1, wn = wid & 1;
  int lr = lane & 15, lk = lane >> 4;
  f32x4 acc[4][4] = {};
  bf16x8 raH[4], rbH[4], raL[4], rbL[4];
  LOAD_STEP(0);
  for (int t = 0; t < kSteps; ++t) {
    __syncthreads();
    #pragma unroll
    for (int q = 0; q < 4; ++q) {
      int rr = r0 + 32 * q;
      *(bf16x8*)&AsH[rr * 64 + cph * 8] = raH[q];
      *(bf16x8*)&BsH[rr * 64 + cph * 8] = rbH[q];
      *(bf16x8*)&AsL[rr * 64 + cph * 8] = raL[q];
      *(bf16x8*)&BsL[rr * 64 + cph * 8] = rbL[q];
    }
    __syncthreads();
    if (t + 1 < kSteps) LOAD_STEP(t + 1);
    #pragma unroll
    for (int kh = 0; kh < 2; ++kh) {
      bf16x8 afH[4], bfH[4], afL[4], bfL[4];
      #pragma unroll
      for (int mf = 0; mf < 4; ++mf) {
        int row = wm * 64 + mf * 16 + lr;
        int ch = (kh * 4 + lk) ^ (row & 7);
        afH[mf] = *(const bf16x8*)&AsH[row * 64 + ch * 8];
        afL[mf] = *(const bf16x8*)&AsL[row * 64 + ch * 8];
      }
      #pragma unroll
      for (int nf = 0; nf < 4; ++nf) {
        int row = wn * 64 + nf * 16 + lr;
        int ch = (kh * 4 + lk) ^ (row & 7);
        bfH[nf] = *(const bf16x8*)&BsH[row * 64 + ch * 8];
        bfL[nf] = *(const bf16x8*)&BsL[row * 64 + ch * 8];
      }
      #pragma unroll
      for (int mf = 0; mf < 4; ++mf)
        #pragma unroll
        for (int nf = 0; nf < 4; ++nf)
          acc[mf][nf] = __builtin_amdgcn_mfma_f32_16x16x32_bf16(afH[mf], bfH[nf], acc[mf][nf], 0, 0, 0);
      #pragma unroll
      for (int mf = 0; mf < 4; ++mf)
        #pragma unroll
        for (int nf = 0; nf < 4; ++nf)
          acc[mf][nf] = __builtin_amdgcn_mfma_f32_16x16x32_bf16(afH[mf], bfL[nf], acc[mf][nf], 0, 0, 0);
      #pragma unroll
      for (int mf = 0; mf < 4; ++mf)
        #pragma unroll
        for (int nf = 0; nf < 4; ++nf)
          acc[mf][nf] = __builtin_amdgcn_mfma_f32_16x16x32_bf16(afL[mf], bfH[nf], acc[mf][nf], 0, 0, 0);
    }
  }
  int crow = bm + wm * 64, ccol = bn + wn * 64;
  if constexpr (EPI == 1) {
    float* C = (float*)Cv;
    #pragma unroll
    for (int mf = 0; mf < 4; ++mf)
      #pragma unroll
      for (int nf = 0; nf < 4; ++nf)
        #pragma unroll
        for (int r = 0; r < 4; ++r) {
          int row = crow + mf * 16 + lk * 4 + r;
          int col = ccol + nf * 16 + lr;
          C[(size_t)row * N + col] = acc[mf][nf][r] + extra[(size_t)row * N + col];
        }
  } else {  // EPI == 4: QKV fused RoPE
    const float qs = 0.125f * 1.44269504088896340736f;
    int seg = (ccol >> 6) % 3;
    int hh = ccol / 192;
    if (seg == 2) {
      #pragma unroll
      for (int mf = 0; mf < 4; ++mf)
        #pragma unroll
        for (int r = 0; r < 4; ++r) {
          int row = crow + mf * 16 + lk * 4 + r;
          size_t ob = (size_t)row * 1024 + hh * 64;
          #pragma unroll
          for (int nf = 0; nf < 4; ++nf)
            vout[ob + nf * 16 + lr] = acc[mf][nf][r];
        }
    } else if (seg == 0) {
      #pragma unroll
      for (int mf = 0; mf < 4; ++mf)
        #pragma unroll
        for (int r = 0; r < 4; ++r) {
          int row = crow + mf * 16 + lk * 4 + r;
          int t = row & (TT - 1);
          size_t qb = (size_t)row * 1024 + hh * 64;
          #pragma unroll
          for (int nf0 = 0; nf0 < 2; ++nf0) {
            int j = nf0 * 16 + lr;
            float s = st[t * 32 + j], c = ct[t * 32 + j];
            float q1 = acc[mf][nf0][r], q2 = acc[mf][nf0 + 2][r];
            float a1 = (q1 * c - q2 * s) * qs;
            float a2 = (q1 * s + q2 * c) * qs;
            ushort u1 = f2bf(a1);
            Qh[qb + j] = u1; Ql[qb + j] = f2bf(a1 - bf2f(u1));
            ushort u2 = f2bf(a2);
            Qh[qb + 32 + j] = u2; Ql[qb + 32 + j] = f2bf(a2 - bf2f(u2));
          }
        }
    } else {
      #pragma unroll
      for (int mf = 0; mf < 4; ++mf)
        #pragma unroll
        for (int r = 0; r < 4; ++r) {
          int row = crow + mf * 16 + lk * 4 + r;
          int t = row & (TT - 1);
          int bb = row >> 11;
          size_t kb = ((size_t)(bb * 16 + hh) * TT + t) * 64;
          size_t ob = (size_t)row * 1024 + hh * 64;
          #pragma unroll
          for (int nf0 = 0; nf0 < 2; ++nf0) {
            int j = nf0 * 16 + lr;
            float s = st[t * 32 + j], c = ct[t * 32 + j];
            float k1 = acc[mf][nf0][r], k2 = acc[mf][nf0 + 2][r];
            float kr1 = k1 * c - k2 * s;
            float kr2 = k1 * s + k2 * c;
            kout[ob + j] = kr1; kout[ob + 32 + j] = kr2;
            ushort u1 = f2bf(kr1);
            Kh[kb + j] = u1; Kl[kb + j] = f2bf(kr1 - bf2f(u1));
            ushort u2 = f2bf(kr2);
            Kh[kb + 32 + j] = u2; Kl[kb + 32 + j] = f2bf(kr2 - bf2f(u2));
          }
        }
    }
  }
}

// ---------------------------------------------------------------- MFMA GEMM, non-split experts: dbuf global_load_lds
// m151 recipe: 2x32KB LDS double buffer, issue-early STAGE, one vmcnt(0)+
// barrier per k-step. Swizzle pairing (linear dest + inv-swz source + same
// XOR on read) = r8-verified. EPI: 2 bf16 gelu(C+bias); 3 bf16 C+bias.
#define STAGE_ND(buf, tt) do {                                                 \
    int kk = (tt) << 6;                                                        \
    _Pragma("unroll")                                                          \
    for (int i = 0; i < 4; ++i) {                                              \
      int row = w32 + i * 8 + lrow;                                            \
      int sc = cph2 ^ (row & 7);                                               \
      gload16(AB + (size_t)garow[i] * K + kk + sc * 8,                         \
              &As[buf][(w32 + i * 8) * 64]);                                   \
      gload16(BB + (size_t)(bn + row) * K + kk + sc * 8,                       \
              &Bs[buf][(w32 + i * 8) * 64]);                                   \
    }                                                                          \
  } while (0)

template<int EPI, bool GATHER>
__global__ __launch_bounds__(256, 2)
void mgemm_nd(const ushort* __restrict__ Ah, const ushort* __restrict__ Bh,
              ushort* __restrict__ Cv, const float* __restrict__ extra,
              const int* __restrict__ gatAll, int N, int K,
              long aEStride, long bEStride, long cEStride, int biasEStride) {
  __shared__ ushort As[2][128 * 64];
  __shared__ ushort Bs[2][128 * 64];
  int z = blockIdx.z;
  const ushort* AB = Ah + (size_t)z * aEStride;
  const ushort* BB = Bh + (size_t)z * bEStride;
  const int* gat = GATHER ? (gatAll + z * 1024) : nullptr;
  int bx = blockIdx.x, by = blockIdx.y;
  {
    int nwg = gridDim.x * gridDim.y;
    if ((nwg & 7) == 0) {
      int lid = bx + by * gridDim.x;
      int cpx = nwg >> 3;
      int wgid = (lid & 7) * cpx + (lid >> 3);
      bx = wgid % gridDim.x;
      by = wgid / gridDim.x;
    }
  }
  int bm = by * 128, bn = bx * 128;
  int tid = threadIdx.x;
  int wid = tid >> 6, lane = tid & 63;
  int w32 = wid * 32;
  int lrow = lane >> 3, cph2 = lane & 7;
  int garow[4];
  #pragma unroll
  for (int i = 0; i < 4; ++i) {
    int row = w32 + i * 8 + lrow;
    garow[i] = GATHER ? gat[bm + row] : (bm + row);
  }
  int kSteps = K >> 6;
  int wm = wid >> 1, wn = wid & 1;
  int lr = lane & 15, lk = lane >> 4;
  f32x4 acc[4][4] = {};

  STAGE_ND(0, 0);
  asm volatile("s_waitcnt vmcnt(0)" ::: "memory");
  __builtin_amdgcn_s_barrier();
  for (int t = 0; t < kSteps; ++t) {
    int cur = t & 1;
    if (t + 1 < kSteps) STAGE_ND(cur ^ 1, t + 1);   // issue-early: overlaps compute
    #pragma unroll
    for (int kh = 0; kh < 2; ++kh) {
      bf16x8 af[4], bfr[4];
      #pragma unroll
      for (int mf = 0; mf < 4; ++mf) {
        int row = wm * 64 + mf * 16 + lr;
        int ch = (kh * 4 + lk) ^ (row & 7);
        af[mf] = *(const bf16x8*)&As[cur][row * 64 + ch * 8];
      }
      #pragma unroll
      for (int nf = 0; nf < 4; ++nf) {
        int row = wn * 64 + nf * 16 + lr;
        int ch = (kh * 4 + lk) ^ (row & 7);
        bfr[nf] = *(const bf16x8*)&Bs[cur][row * 64 + ch * 8];
      }
      #pragma unroll
      for (int mf = 0; mf < 4; ++mf)
        #pragma unroll
        for (int nf = 0; nf < 4; ++nf)
          acc[mf][nf] = __builtin_amdgcn_mfma_f32_16x16x32_bf16(af[mf], bfr[nf], acc[mf][nf], 0, 0, 0);
    }
    asm volatile("s_waitcnt vmcnt(0)" ::: "memory");  // next tile landed
    __builtin_amdgcn_s_barrier();
  }
  int crow = bm + wm * 64, ccol = bn + wn * 64;
  const float* bias = extra + (size_t)z * biasEStride;
  ushort* C = Cv + (size_t)z * cEStride;
  #pragma unroll
  for (int mf = 0; mf < 4; ++mf)
    #pragma unroll
    for (int nf = 0; nf < 4; ++nf)
      #pragma unroll
      for (int r = 0; r < 4; ++r) {
        int row = crow + mf * 16 + lk * 4 + r;
        int col = ccol + nf * 16 + lr;
        float v = acc[mf][nf][r] + bias[col];
        if constexpr (EPI == 2)
          v = 0.5f * v * (1.0f + erff(v * 0.70710678118654752f));
        C[(size_t)row * N + col] = f2bf(v);
      }
}

// ---------------------------------------------------------------- per-expert capacity select v2
__global__ __launch_bounds__(1024)
void route_sort_kernel(const int* __restrict__ te, const float* __restrict__ tv,
                       int* __restrict__ etok, float* __restrict__ ew,
                       int* __restrict__ inv) {
  __shared__ unsigned long long sk[4096];
  __shared__ int wcnt[16];
  __shared__ int base;
  int e = blockIdx.x, tid = threadIdx.x;
  int lane = tid & 63, wv = tid >> 6;
  if (tid == 0) base = 0;
  __syncthreads();
  for (int c = 0; c < 8; ++c) {
    int s = c * 1024 + tid;
    bool sel = (te[s] == e);
    unsigned long long ball = __ballot(sel);
    int pre = __popcll(ball & ((1ull << lane) - 1ull));
    if (lane == 0) wcnt[wv] = __popcll(ball);
    __syncthreads();
    int woff = 0, tot = 0;
    #pragma unroll
    for (int i = 0; i < 16; ++i) {
      int cc = wcnt[i];
      if (i < wv) woff += cc;
      tot += cc;
    }
    if (sel) {
      unsigned vb = __float_as_uint(tv[s]);
      sk[base + woff + pre] =
          ((unsigned long long)vb << 32) | (unsigned)(0xFFFFFFFFu - (unsigned)s);
    }
    __syncthreads();
    if (tid == 0) base += tot;
    __syncthreads();
  }
  int n = base;
  if (n > 1024) {
    int P = (n <= 2048) ? 2048 : 4096;
    for (int i = n + tid; i < P; i += 1024) sk[i] = 0ull;
    __syncthreads();
    for (int k = 2; k <= P; k <<= 1)
      for (int j = k >> 1; j > 0; j >>= 1) {
        for (int t = tid; t < (P >> 1); t += 1024) {
          int i = ((t & ~(j - 1)) << 1) | (t & (j - 1));
          int p = i | j;
          unsigned long long a = sk[i], bq = sk[p];
          bool desc = ((i & k) == 0);
          if (desc ? (a < bq) : (a > bq)) { sk[i] = bq; sk[p] = a; }
        }
        __syncthreads();
      }
  }
  int cap = n < 1024 ? n : 1024;
  if (tid < cap) {
    unsigned long long key = sk[tid];
    unsigned slot = 0xFFFFFFFFu - (unsigned)(key & 0xFFFFFFFFull);
    etok[e * 1024 + tid] = (int)(slot >> 1);
    ew[e * 1024 + tid] = __uint_as_float((unsigned)(key >> 32));
    inv[slot] = e * 1024 + tid;
  } else {
    etok[e * 1024 + tid] = 0;
    ew[e * 1024 + tid] = 0.0f;
  }
}

// ---------------------------------------------------------------- final combine (deterministic)
__global__ __launch_bounds__(256)
void combine_kernel(const float* __restrict__ xres, const ushort* __restrict__ eo,
                    const int* __restrict__ inv, const float* __restrict__ ew,
                    float* __restrict__ outx, float* __restrict__ aux) {
  int token = blockIdx.x;
  int d = threadIdx.x * 4;
  float4 acc = *(const float4*)&xres[(size_t)token * 1024 + d];
  #pragma unroll
  for (int j = 0; j < 2; ++j) {
    int p = inv[token * 2 + j];
    if (p >= 0) {
      float w = ew[p];
      const ushort* ep = eo + (size_t)p * 1024 + d;
      acc.x += w * bf2f(ep[0]); acc.y += w * bf2f(ep[1]);
      acc.z += w * bf2f(ep[2]); acc.w += w * bf2f(ep[3]);
    }
  }
  *(float4*)&outx[(size_t)token * 1024 + d] = acc;
  if (token == 0 && threadIdx.x == 0) aux[0] = 0.0f;
}

// ================================================================ launch
extern "C" void kernel_launch(void* const* d_in, const int* in_sizes, int n_in,
                              void* d_out, int out_size, void* d_ws, size_t ws_size,
                              hipStream_t stream) {
  const float* x     = (const float*)d_in[0];
  const float* ln1g  = (const float*)d_in[1];
  const float* ln1b  = (const float*)d_in[2];
  const float* ln2g  = (const float*)d_in[3];
  const float* ln2b  = (const float*)d_in[4];
  const float* Wqkv  = (const float*)d_in[5];
  const float* Wproj = (const float*)d_in[6];
  const float* Wg    = (const float*)d_in[7];
  const float* W1    = (const float*)d_in[8];
  const float* b1    = (const float*)d_in[9];
  const float* W2    = (const float*)d_in[10];
  const float* b2    = (const float*)d_in[11];

  float* out_x   = (float*)d_out;
  float* out_aux = out_x + 4194304;
  float* out_k   = out_aux + 1;
  float* out_v   = out_k + 4194304;

  float* ws   = (float*)d_ws;
  float* A    = ws;                          // x_res
  ushort* KhQ = (ushort*)(ws + 4194304);     // [2][16][2048][64] bf16
  ushort* KlQ = KhQ + 4194304;
  ushort* Qh_ = (ushort*)(ws + 16777216);    // [4096][1024] bf16 (pre-scaled Q hi)
  ushort* Ql_ = (ushort*)(ws + 18874368);    // [4096][1024] bf16 (lo)
  float* st   = ws + 20971520;
  float* ct   = ws + 21037056;
  int*   te   = (int*)(ws + 21102592);
  float* tv   = ws + 21110784;
  int*   etok = (int*)(ws + 21118976);
  float* ew   = ws + 21127168;
  int*   inv  = (int*)(ws + 21135360);
  ushort* bfAh = (ushort*)(ws + 21143552);   // [4096][1024] bf16
  ushort* bfAl = (ushort*)(ws + 23240704);
  ushort* BqH  = (ushort*)(ws + 25337856);   // WqkvT hi [3072][1024]
  ushort* BqL  = (ushort*)(ws + 26910720);
  ushort* BpH  = (ushort*)(ws + 28483584);   // WprojT hi [1024][1024]
  ushort* BpL  = (ushort*)(ws + 29007872);
  ushort* W1t  = (ushort*)(ws + 29532160);   // [8][4096][1024] (written AFTER fmerge)
  ushort* W2t  = (ushort*)(ws + 46309376);   // [8][1024][4096] (written AFTER fmerge)
  ushort* eo   = (ushort*)(ws + 63086592);   // [8192][1024] bf16
  ushort* hbuf = (ushort*)(ws + 4194304);    // [8][1024][4096] bf16 — reuses KhQ/KlQ
                                             // region AFTER flash/fmerge are done
  ushort* Vth_ = eo;                         // [2][16][64][2048]
  ushort* Vtl_ = eo + 4194304;
  float* Opart = ws + 29532160;              // [1280][128][64] (aliases W1t until fmerge)
  float* Mpart = ws + 40017920;              // [1280][128]
  float* Lpart = ws + 40181760;              // [1280][128]

  // weight prep needed before flash (W1/W2 transposes after fmerge)
  tconv_kernel<true ><<<dim3(96, 32, 1),  dim3(32, 8), 0, stream>>>(Wqkv,  BqH, BqL, 1024, 3072);
  tconv_kernel<true ><<<dim3(32, 32, 1),  dim3(32, 8), 0, stream>>>(Wproj, BpH, BpL, 1024, 1024);
  sincos_kernel<<<TT, 32, 0, stream>>>(st, ct);

  // LN1 (fused bf16 split)
  ln_kernel<false><<<NTOK, 256, 0, stream>>>(x, ln1g, ln1b, bfAh, bfAl,
                                             nullptr, nullptr, nullptr, nullptr);
  // QKV with fused RoPE epilogue: writes Qh/Ql, KhQ/KlQ, out_k, out_v directly.
  mgemm<4><<<dim3(24, 32, 1), 256, 0, stream>>>(
      bfAh, bfAl, BqH, BqL, nullptr, nullptr, 3072, 1024,
      st, ct, out_k, out_v, KhQ, KlQ, Qh_, Ql_);
  vtprep_kernel<<<dim3(32, 16, 2), 256, 0, stream>>>(out_v, Vth_, Vtl_);
  // split-KV flash + merge (merge writes proj-input splits directly)
  flash11_kernel<<<1280, 256, 0, stream>>>(Qh_, Ql_, KhQ, KlQ, Vth_, Vtl_,
                                           Opart, Mpart, Lpart);
  fmerge2_kernel<<<dim3(16, 32), 256, 0, stream>>>(Opart, Mpart, Lpart, bfAh, bfAl);
  // proj + residual (split-bf16, combined 3-term staging)
  mgemm<1><<<dim3(8, 32, 1), 256, 0, stream>>>(
      bfAh, bfAl, BpH, BpL, A, x, 1024, 1024,
      nullptr, nullptr, nullptr, nullptr, nullptr, nullptr, nullptr, nullptr);
  // expert weight prep, vectorized (W1t/W2t regions free after fmerge)
  tconv4_kernel<<<dim3(64, 16, 8), 256, 0, stream>>>(W1, W1t, 1024, 4096);
  tconv4_kernel<<<dim3(16, 64, 8), 256, 0, stream>>>(W2, W2t, 4096, 1024);
  // LN2 + fused gate (bit-identical summation via LDS row staging)
  ln_kernel<true><<<NTOK, 256, 0, stream>>>(A, ln2g, ln2b, bfAh, bfAl, Wg, te, tv, inv);
  route_sort_kernel<<<8, 1024, 0, stream>>>(te, tv, etok, ew, inv);
  // experts (dbuf global_load_lds pipeline): up (gather+gelu -> hbuf), down (-> eo)
  mgemm_nd<2, true><<<dim3(32, 8, 8), 256, 0, stream>>>(
      bfAh, W1t, hbuf, b1, etok, 4096, 1024,
      0, 4096L * 1024, 1024L * 4096, 4096);
  mgemm_nd<3, false><<<dim3(8, 8, 8), 256, 0, stream>>>(
      hbuf, W2t, eo, b2, nullptr, 1024, 4096,
      1024L * 4096, 1024L * 4096, 1024L * 1024, 1024);
  combine_kernel<<<NTOK, 256, 0, stream>>>(A, eo, inv, ew, out_x, out_aux);
}

// Round 19
// 644.739 us; speedup vs baseline: 1.0782x; 1.0782x over previous
//
#include <hip/hip_runtime.h>
#include <hip/hip_bf16.h>
#include <math.h>

// Round 19: revert expert GEMMs to r17 reg-staged path (dbuf/gload_lds
// rejected twice: +40us both times). Add tconv4L = vectorized hi/lo weight
// transpose for Wqkv/Wproj (bit-identical). Everything else = r17 (652us best).
// B=2 T=2048 D=1024 NH=16 HD=64 HALF=32 NEXP=8 TOPK=2 CAP=1024 FF=4096

#define TT 2048
#define NTOK 4096

typedef __attribute__((ext_vector_type(8))) short bf16x8;
typedef __attribute__((ext_vector_type(4))) float f32x4;
typedef __attribute__((ext_vector_type(16))) float f32x16;

static __device__ __forceinline__ ushort f2bf(float f) {
  union { float f; unsigned u; } v; v.f = f;
  unsigned r = v.u + 0x7FFFu + ((v.u >> 16) & 1u);
  return (ushort)(r >> 16);
}
static __device__ __forceinline__ float bf2f(ushort h) {
  union { unsigned u; float f; } v; v.u = ((unsigned)h) << 16; return v.f;
}
static __device__ __forceinline__ unsigned cvt_pk_bf16(float lo, float hi) {
  unsigned r;
  asm("v_cvt_pk_bf16_f32 %0, %1, %2" : "=v"(r) : "v"(lo), "v"(hi));
  return r;
}
static __device__ __forceinline__ void plane_swap(unsigned& a, unsigned& b) {
  asm("v_permlane32_swap_b32 %0, %1" : "+v"(a), "+v"(b));
}
static __device__ __forceinline__ float fexp2(float x) {
  float r;
  asm("v_exp_f32 %0, %1" : "=v"(r) : "v"(x));
  return r;
}

// ---------------------------------------------------------------- LayerNorm (+ bf16 split; GATE: fused router)
template<bool GATE>
__global__ __launch_bounds__(256)
void ln_kernel(const float* __restrict__ x, const float* __restrict__ g,
               const float* __restrict__ b, ushort* __restrict__ oh,
               ushort* __restrict__ ol, const float* __restrict__ Wg,
               int* __restrict__ te, float* __restrict__ tv, int* __restrict__ inv) {
  __shared__ float srow[1024];
  int row = blockIdx.x, tid = threadIdx.x;
  const float4* xr = (const float4*)(x + (size_t)row * 1024);
  float4 v = xr[tid];
  float s = v.x + v.y + v.z + v.w;
  #pragma unroll
  for (int off = 1; off < 64; off <<= 1) s += __shfl_xor(s, off);
  __shared__ float red1[4], red2[4];
  if ((tid & 63) == 0) red1[tid >> 6] = s;
  __syncthreads();
  float mu = (red1[0] + red1[1] + red1[2] + red1[3]) * (1.0f / 1024.0f);
  float dx = v.x - mu, dy = v.y - mu, dz = v.z - mu, dw = v.w - mu;
  float ss = dx*dx + dy*dy + dz*dz + dw*dw;
  #pragma unroll
  for (int off = 1; off < 64; off <<= 1) ss += __shfl_xor(ss, off);
  if ((tid & 63) == 0) red2[tid >> 6] = ss;
  __syncthreads();
  float var = (red2[0] + red2[1] + red2[2] + red2[3]) * (1.0f / 1024.0f);
  float inv_ = 1.0f / sqrtf(var + 1e-5f);
  float4 g4 = ((const float4*)g)[tid];
  float4 b4 = ((const float4*)b)[tid];
  float4 o4;
  o4.x = dx * inv_ * g4.x + b4.x;
  o4.y = dy * inv_ * g4.y + b4.y;
  o4.z = dz * inv_ * g4.z + b4.z;
  o4.w = dw * inv_ * g4.w + b4.w;
  size_t base = (size_t)row * 1024 + tid * 4;
  ushort h0 = f2bf(o4.x), h1 = f2bf(o4.y), h2 = f2bf(o4.z), h3 = f2bf(o4.w);
  ushort4 hh = {h0, h1, h2, h3};
  *(ushort4*)(oh + base) = hh;
  ushort4 ll = {f2bf(o4.x - bf2f(h0)), f2bf(o4.y - bf2f(h1)),
                f2bf(o4.z - bf2f(h2)), f2bf(o4.w - bf2f(h3))};
  *(ushort4*)(ol + base) = ll;
  if constexpr (GATE) {
    *(float4*)&srow[tid * 4] = o4;
    __syncthreads();
    float acc[8] = {};
    for (int i = tid; i < 1024; i += 256) {
      float xv = srow[i];
      const float4* wr = (const float4*)&Wg[i * 8];
      float4 w0 = wr[0], w1 = wr[1];
      acc[0] += xv * w0.x; acc[1] += xv * w0.y; acc[2] += xv * w0.z; acc[3] += xv * w0.w;
      acc[4] += xv * w1.x; acc[5] += xv * w1.y; acc[6] += xv * w1.z; acc[7] += xv * w1.w;
    }
    #pragma unroll
    for (int off = 1; off < 64; off <<= 1)
      #pragma unroll
      for (int qq = 0; qq < 8; ++qq) acc[qq] += __shfl_xor(acc[qq], off);
    __shared__ float red[4][8];
    if ((tid & 63) == 0)
      #pragma unroll
      for (int qq = 0; qq < 8; ++qq) red[tid >> 6][qq] = acc[qq];
    __syncthreads();
    if (tid == 0) {
      float gg[8];
      #pragma unroll
      for (int qq = 0; qq < 8; ++qq) gg[qq] = red[0][qq] + red[1][qq] + red[2][qq] + red[3][qq];
      float mx = gg[0];
      #pragma unroll
      for (int qq = 1; qq < 8; ++qq) mx = fmaxf(mx, gg[qq]);
      float sum = 0.0f;
      #pragma unroll
      for (int qq = 0; qq < 8; ++qq) { gg[qq] = expf(gg[qq] - mx); sum += gg[qq]; }
      float inv_s = 1.0f / sum;
      #pragma unroll
      for (int qq = 0; qq < 8; ++qq) gg[qq] *= inv_s;
      int e1 = 0; float v1 = gg[0];
      for (int qq = 1; qq < 8; ++qq) if (gg[qq] > v1) { v1 = gg[qq]; e1 = qq; }
      int e2 = -1; float v2 = -1.0f;
      for (int qq = 0; qq < 8; ++qq) { if (qq == e1) continue; if (gg[qq] > v2) { v2 = gg[qq]; e2 = qq; } }
      te[row * 2] = e1; te[row * 2 + 1] = e2;
      tv[row * 2] = v1; tv[row * 2 + 1] = v2;
      inv[row * 2] = -1; inv[row * 2 + 1] = -1;
    }
  }
}

// ---------------------------------------------------------------- RoPE tables (f64)
__global__ void sincos_kernel(float* __restrict__ st, float* __restrict__ ct) {
  int t = blockIdx.x, j = threadIdx.x;
  double invf = pow(10000.0, -((double)(2 * j)) / 64.0);
  double ang = (double)t * invf;
  st[t * 32 + j] = (float)sin(ang);
  ct[t * 32 + j] = (float)cos(ang);
}

// ---------------------------------------------------------------- V^T prep: [b,t,h*64] f32 -> [b,h,64,t] bf16 hi/lo
__global__ __launch_bounds__(256)
void vtprep_kernel(const float* __restrict__ vout, ushort* __restrict__ Vth,
                   ushort* __restrict__ Vtl) {
  __shared__ float tile[64][65];
  int t0 = blockIdx.x * 64, h = blockIdx.y, b = blockIdx.z;
  int tid = threadIdx.x;
  #pragma unroll
  for (int l = 0; l < 4; ++l) {
    int idx = l * 256 + tid;
    int r = idx >> 4, c4 = (idx & 15) * 4;
    *(float4*)&tile[r][c4] = *(const float4*)&vout[((size_t)(b * TT + t0 + r)) * 1024 + h * 64 + c4];
  }
  __syncthreads();
  int d = tid >> 2, ts = (tid & 3) * 16;
  union { bf16x8 v; ushort u[8]; } H0, H1, L0, L1;
  #pragma unroll
  for (int i = 0; i < 8; ++i) {
    float v0 = tile[ts + i][d];
    ushort hb0 = f2bf(v0);
    H0.u[i] = hb0; L0.u[i] = f2bf(v0 - bf2f(hb0));
    float v1 = tile[ts + 8 + i][d];
    ushort hb1 = f2bf(v1);
    H1.u[i] = hb1; L1.u[i] = f2bf(v1 - bf2f(hb1));
  }
  size_t basep = ((size_t)(b * 16 + h) * 64 + d) * TT + t0 + ts;
  *(bf16x8*)(Vth + basep) = H0.v;  *(bf16x8*)(Vth + basep + 8) = H1.v;
  *(bf16x8*)(Vtl + basep) = L0.v;  *(bf16x8*)(Vtl + basep + 8) = L1.v;
}

// ---------------------------------------------------------------- flash v11 (unchanged)
__global__ __launch_bounds__(256)
void flash11_kernel(const ushort* __restrict__ Qh, const ushort* __restrict__ Ql,
                    const ushort* __restrict__ Kh, const ushort* __restrict__ Kl,
                    const ushort* __restrict__ Vth, const ushort* __restrict__ Vtl,
                    float* __restrict__ Opart, float* __restrict__ Mpart,
                    float* __restrict__ Lpart) {
  int lin = blockIdx.x;                     // 1280
  int xcd = lin & 7, s = lin >> 3;
  int bh = xcd + 8 * (s / 40);
  int j = 39 - (s % 40);
  int qt, kc;
  if (j < 4)       { qt = j;                    kc = 0; }
  else if (j < 12) { qt = 4 + ((j - 4) >> 1);   kc = (j - 4) & 1; }
  else if (j < 24) { qt = 8 + (j - 12) / 3;     kc = (j - 12) % 3; }
  else             { qt = 12 + ((j - 24) >> 2); kc = (j - 24) & 3; }
  int slot = bh * 40 + j;
  int h = bh & 15, b = bh >> 4;
  int tid = threadIdx.x;
  int w = tid >> 6, lane = tid & 63;
  int q = lane & 31, LH = lane >> 5;
  size_t bT = (size_t)b * TT;
  int qglob0 = qt * 128 + w * 32;
  int qg = qglob0 + q;
  bf16x8 qH[4], qL[4];
  {
    const ushort* qph = Qh + (bT + qg) * 1024 + h * 64 + LH * 8;
    const ushort* qpl = Ql + (bT + qg) * 1024 + h * 64 + LH * 8;
    #pragma unroll
    for (int dblk = 0; dblk < 4; ++dblk) {
      qH[dblk] = *(const bf16x8*)(qph + dblk * 16);
      qL[dblk] = *(const bf16x8*)(qpl + dblk * 16);
    }
  }
  const ushort* Kbh = Kh + (size_t)bh * TT * 64;
  const ushort* Kbl = Kl + (size_t)bh * TT * 64;
  const ushort* Vbh = Vth + (size_t)bh * 64 * TT;
  const ushort* Vbl = Vtl + (size_t)bh * 64 * TT;
  f32x16 accO0 = {}, accO1 = {};
  float m = -3.402823466e38f, lsum = 0.0f;
  int kvlo = kc * 512;
  int kvhi = min(kvlo + 512, qglob0 + 32);

  auto loadK = [&](bf16x8 (&kH)[4], bf16x8 (&kL)[4], int kv0) {
    const ushort* kbh = Kbh + (size_t)(kv0 + q) * 64 + LH * 8;
    const ushort* kbl = Kbl + (size_t)(kv0 + q) * 64 + LH * 8;
    #pragma unroll
    for (int dblk = 0; dblk < 4; ++dblk) {
      kH[dblk] = *(const bf16x8*)(kbh + dblk * 16);
      kL[dblk] = *(const bf16x8*)(kbl + dblk * 16);
    }
  };

  auto tile = [&](bf16x8 (&kH)[4], bf16x8 (&kL)[4],
                  bf16x8 (&kHn)[4], bf16x8 (&kLn)[4], int kv0, bool pf) {
    bf16x8 vAH[2][2], vAL[2][2];
    #pragma unroll
    for (int dblk = 0; dblk < 2; ++dblk)
      #pragma unroll
      for (int s2 = 0; s2 < 2; ++s2) {
        size_t ad = (size_t)(dblk * 32 + q) * TT + kv0 + s2 * 16 + LH * 8;
        vAH[dblk][s2] = *(const bf16x8*)(Vbh + ad);
        vAL[dblk][s2] = *(const bf16x8*)(Vbl + ad);
      }
    f32x16 sa = {}, sb = {};
    __builtin_amdgcn_s_setprio(1);
    sa = __builtin_amdgcn_mfma_f32_32x32x16_bf16(kH[0], qH[0], sa, 0, 0, 0);
    sb = __builtin_amdgcn_mfma_f32_32x32x16_bf16(kH[2], qH[2], sb, 0, 0, 0);
    sa = __builtin_amdgcn_mfma_f32_32x32x16_bf16(kH[1], qH[1], sa, 0, 0, 0);
    sb = __builtin_amdgcn_mfma_f32_32x32x16_bf16(kH[3], qH[3], sb, 0, 0, 0);
    sa = __builtin_amdgcn_mfma_f32_32x32x16_bf16(kH[0], qL[0], sa, 0, 0, 0);
    sb = __builtin_amdgcn_mfma_f32_32x32x16_bf16(kH[2], qL[2], sb, 0, 0, 0);
    sa = __builtin_amdgcn_mfma_f32_32x32x16_bf16(kH[1], qL[1], sa, 0, 0, 0);
    sb = __builtin_amdgcn_mfma_f32_32x32x16_bf16(kH[3], qL[3], sb, 0, 0, 0);
    sa = __builtin_amdgcn_mfma_f32_32x32x16_bf16(kL[0], qH[0], sa, 0, 0, 0);
    sb = __builtin_amdgcn_mfma_f32_32x32x16_bf16(kL[2], qH[2], sb, 0, 0, 0);
    sa = __builtin_amdgcn_mfma_f32_32x32x16_bf16(kL[1], qH[1], sa, 0, 0, 0);
    sb = __builtin_amdgcn_mfma_f32_32x32x16_bf16(kL[3], qH[3], sb, 0, 0, 0);
    __builtin_amdgcn_s_setprio(0);
    if (pf) loadK(kHn, kLn, kv0 + 32);
    float p[16];
    float pmax = -3.402823466e38f;
    if (kv0 + 31 > qglob0) {
      #pragma unroll
      for (int r = 0; r < 16; ++r) {
        int kvg = kv0 + (r & 3) + 8 * (r >> 2) + 4 * LH;
        float sv = (kvg <= qg) ? (sa[r] + sb[r]) : -3.402823466e38f;
        p[r] = sv; pmax = fmaxf(pmax, sv);
      }
    } else {
      #pragma unroll
      for (int r = 0; r < 16; ++r) {
        float sv = sa[r] + sb[r];
        p[r] = sv; pmax = fmaxf(pmax, sv);
      }
    }
    pmax = fmaxf(pmax, __shfl_xor(pmax, 32));
    float mnew = fmaxf(m, pmax);
    float fsc = fexp2(m - mnew);
    float psum = 0.0f;
    #pragma unroll
    for (int r = 0; r < 16; ++r) { p[r] = fexp2(p[r] - mnew); psum += p[r]; }
    psum += __shfl_xor(psum, 32);
    lsum = lsum * fsc + psum;
    m = mnew;
    #pragma unroll
    for (int r = 0; r < 16; ++r) { accO0[r] *= fsc; accO1[r] *= fsc; }
    bf16x8 pHf[2], pLf[2];
    #pragma unroll
    for (int s2 = 0; s2 < 2; ++s2) {
      int s8 = s2 * 8;
      unsigned a  = cvt_pk_bf16(p[s8 + 0], p[s8 + 1]);
      unsigned bw = cvt_pk_bf16(p[s8 + 2], p[s8 + 3]);
      unsigned c  = cvt_pk_bf16(p[s8 + 4], p[s8 + 5]);
      unsigned d  = cvt_pk_bf16(p[s8 + 6], p[s8 + 7]);
      float l0 = p[s8 + 0] - __uint_as_float(a << 16);
      float l1 = p[s8 + 1] - __uint_as_float(a & 0xFFFF0000u);
      float l2 = p[s8 + 2] - __uint_as_float(bw << 16);
      float l3 = p[s8 + 3] - __uint_as_float(bw & 0xFFFF0000u);
      float l4 = p[s8 + 4] - __uint_as_float(c << 16);
      float l5 = p[s8 + 5] - __uint_as_float(c & 0xFFFF0000u);
      float l6 = p[s8 + 6] - __uint_as_float(d << 16);
      float l7 = p[s8 + 7] - __uint_as_float(d & 0xFFFF0000u);
      unsigned al = cvt_pk_bf16(l0, l1);
      unsigned bl = cvt_pk_bf16(l2, l3);
      unsigned cl = cvt_pk_bf16(l4, l5);
      unsigned dl = cvt_pk_bf16(l6, l7);
      plane_swap(a, c); plane_swap(bw, d);
      plane_swap(al, cl); plane_swap(bl, dl);
      union { unsigned w[4]; bf16x8 v; } PH, PL;
      PH.w[0] = a;  PH.w[1] = bw; PH.w[2] = c;  PH.w[3] = d;
      PL.w[0] = al; PL.w[1] = bl; PL.w[2] = cl; PL.w[3] = dl;
      pHf[s2] = PH.v; pLf[s2] = PL.v;
    }
    __builtin_amdgcn_s_setprio(1);
    #pragma unroll
    for (int s2 = 0; s2 < 2; ++s2) {
      accO0 = __builtin_amdgcn_mfma_f32_32x32x16_bf16(vAH[0][s2], pHf[s2], accO0, 0, 0, 0);
      accO1 = __builtin_amdgcn_mfma_f32_32x32x16_bf16(vAH[1][s2], pHf[s2], accO1, 0, 0, 0);
      accO0 = __builtin_amdgcn_mfma_f32_32x32x16_bf16(vAH[0][s2], pLf[s2], accO0, 0, 0, 0);
      accO1 = __builtin_amdgcn_mfma_f32_32x32x16_bf16(vAH[1][s2], pLf[s2], accO1, 0, 0, 0);
      accO0 = __builtin_amdgcn_mfma_f32_32x32x16_bf16(vAL[0][s2], pHf[s2], accO0, 0, 0, 0);
      accO1 = __builtin_amdgcn_mfma_f32_32x32x16_bf16(vAL[1][s2], pHf[s2], accO1, 0, 0, 0);
    }
    __builtin_amdgcn_s_setprio(0);
  };

  bf16x8 kA[4], kB[4], kC[4], kD[4];
  loadK(kA, kB, kvlo);
  for (int kv0 = kvlo; kv0 < kvhi; kv0 += 64) {
    tile(kA, kB, kC, kD, kv0, kv0 + 32 < kvhi);
    if (kv0 + 32 < kvhi)
      tile(kC, kD, kA, kB, kv0 + 32, kv0 + 64 < kvhi);
  }

  if (LH == 0) {
    Mpart[slot * 128 + w * 32 + q] = m;      // log2 domain
    Lpart[slot * 128 + w * 32 + q] = lsum;
  }
  float* Ob = Opart + (size_t)slot * 8192 + (w * 32 + q) * 64;
  #pragma unroll
  for (int g2 = 0; g2 < 4; ++g2) {
    float4 v0 = {accO0[g2 * 4 + 0], accO0[g2 * 4 + 1], accO0[g2 * 4 + 2], accO0[g2 * 4 + 3]};
    *(float4*)(Ob + 8 * g2 + 4 * LH) = v0;
    float4 v1 = {accO1[g2 * 4 + 0], accO1[g2 * 4 + 1], accO1[g2 * 4 + 2], accO1[g2 * 4 + 3]};
    *(float4*)(Ob + 32 + 8 * g2 + 4 * LH) = v1;
  }
}

// ---------------------------------------------------------------- merge partials (exp2) -> bf16 hi/lo split
__global__ __launch_bounds__(256)
void fmerge2_kernel(const float* __restrict__ Opart, const float* __restrict__ Mpart,
                    const float* __restrict__ Lpart, ushort* __restrict__ oh,
                    ushort* __restrict__ ol) {
  int qt = blockIdx.x, bh = blockIdx.y;
  int h = bh & 15, b = bh >> 4;
  int g = qt >> 2;
  int nc = g + 1;
  int off = 2 * g * (g + 1) + (qt & 3) * (g + 1);
  int slot0 = bh * 40 + off;
  int tid = threadIdx.x;
  int q = tid & 127, dh = tid >> 7;
  float mg = -3.402823466e38f;
  for (int c = 0; c < nc; ++c) mg = fmaxf(mg, Mpart[(slot0 + c) * 128 + q]);
  float lg = 0.0f;
  float4 acc[8] = {};
  for (int c = 0; c < nc; ++c) {
    float sc = fexp2(Mpart[(slot0 + c) * 128 + q] - mg);
    lg += sc * Lpart[(slot0 + c) * 128 + q];
    const float4* op = (const float4*)(Opart + (size_t)(slot0 + c) * 8192 + q * 64 + dh * 32);
    #pragma unroll
    for (int i = 0; i < 8; ++i) {
      float4 v = op[i];
      acc[i].x += sc * v.x; acc[i].y += sc * v.y;
      acc[i].z += sc * v.z; acc[i].w += sc * v.w;
    }
  }
  float inv = 1.0f / lg;
  size_t obase = ((size_t)(b * TT + qt * 128 + q)) * 1024 + h * 64 + dh * 32;
  #pragma unroll
  for (int i = 0; i < 8; ++i) {
    float4 v = {acc[i].x * inv, acc[i].y * inv, acc[i].z * inv, acc[i].w * inv};
    ushort h0 = f2bf(v.x), h1 = f2bf(v.y), h2 = f2bf(v.z), h3 = f2bf(v.w);
    ushort4 hh = {h0, h1, h2, h3};
    *(ushort4*)(oh + obase + i * 4) = hh;
    ushort4 ll = {f2bf(v.x - bf2f(h0)), f2bf(v.y - bf2f(h1)),
                  f2bf(v.z - bf2f(h2)), f2bf(v.w - bf2f(h3))};
    *(ushort4*)(ol + obase + i * 4) = ll;
  }
}

// ---------------------------------------------------------------- tconv4: vectorized transpose+convert (W1/W2)
__global__ __launch_bounds__(256)
void tconv4_kernel(const float* __restrict__ in, ushort* __restrict__ out,
                   int K, int N) {
  __shared__ float t[64][68];
  int z = blockIdx.z;
  const float* ip = in + (size_t)z * K * N;
  ushort* op = out + (size_t)z * K * N;
  int n0 = blockIdx.x * 64, k0 = blockIdx.y * 64;
  int tid = threadIdx.x;
  int r = tid >> 4, c4 = (tid & 15) * 4;
  #pragma unroll
  for (int i = 0; i < 4; ++i)
    *(float4*)&t[r + 16 * i][c4] = *(const float4*)&ip[(size_t)(k0 + r + 16 * i) * N + n0 + c4];
  __syncthreads();
  int n = tid >> 2, kb = (tid & 3) * 16;
  union { ushort u[16]; ushort4 v[4]; } o;
  #pragma unroll
  for (int i = 0; i < 16; ++i) o.u[i] = f2bf(t[kb + i][n]);
  size_t ob = (size_t)(n0 + n) * K + k0 + kb;
  #pragma unroll
  for (int i = 0; i < 4; ++i) *(ushort4*)&op[ob + 4 * i] = o.v[i];
}

// ---------------------------------------------------------------- tconv4L: vectorized transpose + hi/lo convert
__global__ __launch_bounds__(256)
void tconv4L_kernel(const float* __restrict__ in, ushort* __restrict__ oh,
                    ushort* __restrict__ ol, int K, int N) {
  __shared__ float t[64][68];
  const float* ip = in;
  int n0 = blockIdx.x * 64, k0 = blockIdx.y * 64;
  int tid = threadIdx.x;
  int r = tid >> 4, c4 = (tid & 15) * 4;
  #pragma unroll
  for (int i = 0; i < 4; ++i)
    *(float4*)&t[r + 16 * i][c4] = *(const float4*)&ip[(size_t)(k0 + r + 16 * i) * N + n0 + c4];
  __syncthreads();
  int n = tid >> 2, kb = (tid & 3) * 16;
  union { ushort u[16]; ushort4 v[4]; } H, L;
  #pragma unroll
  for (int i = 0; i < 16; ++i) {
    float v = t[kb + i][n];
    ushort hb = f2bf(v);
    H.u[i] = hb;
    L.u[i] = f2bf(v - bf2f(hb));
  }
  size_t ob = (size_t)(n0 + n) * K + k0 + kb;
  #pragma unroll
  for (int i = 0; i < 4; ++i) {
    *(ushort4*)&oh[ob + 4 * i] = H.v[i];
    *(ushort4*)&ol[ob + 4 * i] = L.v[i];
  }
}

// ---------------------------------------------------------------- MFMA GEMM (combined split-3 staging, T1 swizzle)
// EPI: 0 fp32 C; 1 fp32 C+extra; 2 bf16 gelu(C+bias); 3 bf16 C+bias;
//      4 QKV fused-RoPE epilogue (writes Qh/Ql, Kh/Kl, out_k, out_v).
#define LOAD_STEP(tt) do {                                                     \
    int kk = (tt) << 6;                                                        \
    _Pragma("unroll")                                                          \
    for (int q = 0; q < 4; ++q) {                                              \
      int rr = r0 + 32 * q;                                                    \
      int clog = cph ^ (rr & 7);                                               \
      raH[q] = *(const bf16x8*)(AhB + (size_t)garow[q] * K + kk + clog * 8);   \
      rbH[q] = *(const bf16x8*)(BhB + (size_t)(bn + rr) * K + kk + clog * 8);  \
      if constexpr (SPLIT3) {                                                  \
        raL[q] = *(const bf16x8*)(AlB + (size_t)garow[q] * K + kk + clog * 8); \
        rbL[q] = *(const bf16x8*)(BlB + (size_t)(bn + rr) * K + kk + clog * 8);\
      }                                                                        \
    }                                                                          \
  } while (0)

template<int EPI, bool GATHER, bool SPLIT3>
__global__ __launch_bounds__(256, 2)
void mgemm(const ushort* __restrict__ Ah, const ushort* __restrict__ Al,
           const ushort* __restrict__ Bh, const ushort* __restrict__ Bl,
           void* __restrict__ Cv, const float* __restrict__ extra,
           const int* __restrict__ gatAll, int N, int K,
           long aEStride, long bEStride, long cEStride, int biasEStride,
           const float* __restrict__ st, const float* __restrict__ ct,
           float* __restrict__ kout, float* __restrict__ vout,
           ushort* __restrict__ Kh, ushort* __restrict__ Kl,
           ushort* __restrict__ Qh, ushort* __restrict__ Ql) {
  __shared__ ushort As[(SPLIT3 ? 2 : 1) * 128 * 64];
  __shared__ ushort Bs[(SPLIT3 ? 2 : 1) * 128 * 64];
  ushort* AsH = As;  ushort* AsL = SPLIT3 ? (As + 128 * 64) : As;
  ushort* BsH = Bs;  ushort* BsL = SPLIT3 ? (Bs + 128 * 64) : Bs;
  int z = blockIdx.z;
  const ushort* AhB = Ah + (size_t)z * aEStride;
  const ushort* AlB = SPLIT3 ? (Al + (size_t)z * aEStride) : nullptr;
  const ushort* BhB = Bh + (size_t)z * bEStride;
  const ushort* BlB = SPLIT3 ? (Bl + (size_t)z * bEStride) : nullptr;
  const int* gat = GATHER ? (gatAll + z * 1024) : nullptr;
  int bx = blockIdx.x, by = blockIdx.y;
  {
    int nwg = gridDim.x * gridDim.y;
    if ((nwg & 7) == 0) {
      int lid = bx + by * gridDim.x;
      int cpx = nwg >> 3;
      int wgid = (lid & 7) * cpx + (lid >> 3);
      bx = wgid % gridDim.x;
      by = wgid / gridDim.x;
    }
  }
  int bm = by * 128, bn = bx * 128;
  int tid = threadIdx.x;
  int r0 = tid >> 3, cph = tid & 7;
  int garow[4];
  #pragma unroll
  for (int q = 0; q < 4; ++q) {
    int rr = r0 + 32 * q;
    garow[q] = GATHER ? gat[bm + rr] : (bm + rr);
  }
  int kSteps = K >> 6;
  int wid = tid >> 6, lane = tid & 63;
  int wm = wid >> 1, wn = wid & 1;
  int lr = lane & 15, lk = lane >> 4;
  f32x4 acc[4][4] = {};
  bf16x8 raH[4], rbH[4], raL[4], rbL[4];
  LOAD_STEP(0);
  for (int t = 0; t < kSteps; ++t) {
    __syncthreads();
    #pragma unroll
    for (int q = 0; q < 4; ++q) {
      int rr = r0 + 32 * q;
      *(bf16x8*)&AsH[rr * 64 + cph * 8] = raH[q];
      *(bf16x8*)&BsH[rr * 64 + cph * 8] = rbH[q];
      if constexpr (SPLIT3) {
        *(bf16x8*)&AsL[rr * 64 + cph * 8] = raL[q];
        *(bf16x8*)&BsL[rr * 64 + cph * 8] = rbL[q];
      }
    }
    __syncthreads();
    if (t + 1 < kSteps) LOAD_STEP(t + 1);
    #pragma unroll
    for (int kh = 0; kh < 2; ++kh) {
      bf16x8 afH[4], bfH[4], afL[4], bfL[4];
      #pragma unroll
      for (int mf = 0; mf < 4; ++mf) {
        int row = wm * 64 + mf * 16 + lr;
        int ch = (kh * 4 + lk) ^ (row & 7);
        afH[mf] = *(const bf16x8*)&AsH[row * 64 + ch * 8];
        if constexpr (SPLIT3) afL[mf] = *(const bf16x8*)&AsL[row * 64 + ch * 8];
      }
      #pragma unroll
      for (int nf = 0; nf < 4; ++nf) {
        int row = wn * 64 + nf * 16 + lr;
        int ch = (kh * 4 + lk) ^ (row & 7);
        bfH[nf] = *(const bf16x8*)&BsH[row * 64 + ch * 8];
        if constexpr (SPLIT3) bfL[nf] = *(const bf16x8*)&BsL[row * 64 + ch * 8];
      }
      #pragma unroll
      for (int mf = 0; mf < 4; ++mf)
        #pragma unroll
        for (int nf = 0; nf < 4; ++nf)
          acc[mf][nf] = __builtin_amdgcn_mfma_f32_16x16x32_bf16(afH[mf], bfH[nf], acc[mf][nf], 0, 0, 0);
      if constexpr (SPLIT3) {
        #pragma unroll
        for (int mf = 0; mf < 4; ++mf)
          #pragma unroll
          for (int nf = 0; nf < 4; ++nf)
            acc[mf][nf] = __builtin_amdgcn_mfma_f32_16x16x32_bf16(afH[mf], bfL[nf], acc[mf][nf], 0, 0, 0);
        #pragma unroll
        for (int mf = 0; mf < 4; ++mf)
          #pragma unroll
          for (int nf = 0; nf < 4; ++nf)
            acc[mf][nf] = __builtin_amdgcn_mfma_f32_16x16x32_bf16(afL[mf], bfH[nf], acc[mf][nf], 0, 0, 0);
      }
    }
  }
  int crow = bm + wm * 64, ccol = bn + wn * 64;
  if constexpr (EPI <= 1) {
    float* C = (float*)Cv;
    #pragma unroll
    for (int mf = 0; mf < 4; ++mf)
      #pragma unroll
      for (int nf = 0; nf < 4; ++nf)
        #pragma unroll
        for (int r = 0; r < 4; ++r) {
          int row = crow + mf * 16 + lk * 4 + r;
          int col = ccol + nf * 16 + lr;
          float v = acc[mf][nf][r];
          if constexpr (EPI == 1) v += extra[(size_t)row * N + col];
          C[(size_t)row * N + col] = v;
        }
  } else if constexpr (EPI == 4) {
    // QKV fused RoPE: wave's 64-col tile lies in exactly one {q,k,v} segment.
    const float qs = 0.125f * 1.44269504088896340736f;
    int seg = (ccol >> 6) % 3;
    int hh = ccol / 192;
    if (seg == 2) {                       // V: fp32 copy-out to [row][h*64+d]
      #pragma unroll
      for (int mf = 0; mf < 4; ++mf)
        #pragma unroll
        for (int r = 0; r < 4; ++r) {
          int row = crow + mf * 16 + lk * 4 + r;
          size_t ob = (size_t)row * 1024 + hh * 64;
          #pragma unroll
          for (int nf = 0; nf < 4; ++nf)
            vout[ob + nf * 16 + lr] = acc[mf][nf][r];
        }
    } else if (seg == 0) {                // Q: rotate + pre-scale -> bf16 hi/lo
      #pragma unroll
      for (int mf = 0; mf < 4; ++mf)
        #pragma unroll
        for (int r = 0; r < 4; ++r) {
          int row = crow + mf * 16 + lk * 4 + r;
          int t = row & (TT - 1);
          size_t qb = (size_t)row * 1024 + hh * 64;
          #pragma unroll
          for (int nf0 = 0; nf0 < 2; ++nf0) {
            int j = nf0 * 16 + lr;
            float s = st[t * 32 + j], c = ct[t * 32 + j];
            float q1 = acc[mf][nf0][r], q2 = acc[mf][nf0 + 2][r];
            float a1 = (q1 * c - q2 * s) * qs;
            float a2 = (q1 * s + q2 * c) * qs;
            ushort u1 = f2bf(a1);
            Qh[qb + j] = u1; Ql[qb + j] = f2bf(a1 - bf2f(u1));
            ushort u2 = f2bf(a2);
            Qh[qb + 32 + j] = u2; Ql[qb + 32 + j] = f2bf(a2 - bf2f(u2));
          }
        }
    } else {                              // K: rotate -> out_k fp32 + Kh/Kl
      #pragma unroll
      for (int mf = 0; mf < 4; ++mf)
        #pragma unroll
        for (int r = 0; r < 4; ++r) {
          int row = crow + mf * 16 + lk * 4 + r;
          int t = row & (TT - 1);
          int bb = row >> 11;
          size_t kb = ((size_t)(bb * 16 + hh) * TT + t) * 64;
          size_t ob = (size_t)row * 1024 + hh * 64;
          #pragma unroll
          for (int nf0 = 0; nf0 < 2; ++nf0) {
            int j = nf0 * 16 + lr;
            float s = st[t * 32 + j], c = ct[t * 32 + j];
            float k1 = acc[mf][nf0][r], k2 = acc[mf][nf0 + 2][r];
            float kr1 = k1 * c - k2 * s;
            float kr2 = k1 * s + k2 * c;
            kout[ob + j] = kr1; kout[ob + 32 + j] = kr2;
            ushort u1 = f2bf(kr1);
            Kh[kb + j] = u1; Kl[kb + j] = f2bf(kr1 - bf2f(u1));
            ushort u2 = f2bf(kr2);
            Kh[kb + 32 + j] = u2; Kl[kb + 32 + j] = f2bf(kr2 - bf2f(u2));
          }
        }
    }
  } else {
    const float* bias = extra + (size_t)z * biasEStride;
    ushort* C = (ushort*)Cv + (size_t)z * cEStride;
    #pragma unroll
    for (int mf = 0; mf < 4; ++mf)
      #pragma unroll
      for (int nf = 0; nf < 4; ++nf)
        #pragma unroll
        for (int r = 0; r < 4; ++r) {
          int row = crow + mf * 16 + lk * 4 + r;
          int col = ccol + nf * 16 + lr;
          float v = acc[mf][nf][r] + bias[col];
          if constexpr (EPI == 2)
            v = 0.5f * v * (1.0f + erff(v * 0.70710678118654752f));
          C[(size_t)row * N + col] = f2bf(v);
        }
  }
}

// ---------------------------------------------------------------- per-expert capacity select v2
__global__ __launch_bounds__(1024)
void route_sort_kernel(const int* __restrict__ te, const float* __restrict__ tv,
                       int* __restrict__ etok, float* __restrict__ ew,
                       int* __restrict__ inv) {
  __shared__ unsigned long long sk[4096];
  __shared__ int wcnt[16];
  __shared__ int base;
  int e = blockIdx.x, tid = threadIdx.x;
  int lane = tid & 63, wv = tid >> 6;
  if (tid == 0) base = 0;
  __syncthreads();
  for (int c = 0; c < 8; ++c) {
    int s = c * 1024 + tid;
    bool sel = (te[s] == e);
    unsigned long long ball = __ballot(sel);
    int pre = __popcll(ball & ((1ull << lane) - 1ull));
    if (lane == 0) wcnt[wv] = __popcll(ball);
    __syncthreads();
    int woff = 0, tot = 0;
    #pragma unroll
    for (int i = 0; i < 16; ++i) {
      int cc = wcnt[i];
      if (i < wv) woff += cc;
      tot += cc;
    }
    if (sel) {
      unsigned vb = __float_as_uint(tv[s]);
      sk[base + woff + pre] =
          ((unsigned long long)vb << 32) | (unsigned)(0xFFFFFFFFu - (unsigned)s);
    }
    __syncthreads();
    if (tid == 0) base += tot;
    __syncthreads();
  }
  int n = base;
  if (n > 1024) {
    int P = (n <= 2048) ? 2048 : 4096;
    for (int i = n + tid; i < P; i += 1024) sk[i] = 0ull;
    __syncthreads();
    for (int k = 2; k <= P; k <<= 1)
      for (int j = k >> 1; j > 0; j >>= 1) {
        for (int t = tid; t < (P >> 1); t += 1024) {
          int i = ((t & ~(j - 1)) << 1) | (t & (j - 1));
          int p = i | j;
          unsigned long long a = sk[i], bq = sk[p];
          bool desc = ((i & k) == 0);
          if (desc ? (a < bq) : (a > bq)) { sk[i] = bq; sk[p] = a; }
        }
        __syncthreads();
      }
  }
  int cap = n < 1024 ? n : 1024;
  if (tid < cap) {
    unsigned long long key = sk[tid];
    unsigned slot = 0xFFFFFFFFu - (unsigned)(key & 0xFFFFFFFFull);
    etok[e * 1024 + tid] = (int)(slot >> 1);
    ew[e * 1024 + tid] = __uint_as_float((unsigned)(key >> 32));
    inv[slot] = e * 1024 + tid;
  } else {
    etok[e * 1024 + tid] = 0;
    ew[e * 1024 + tid] = 0.0f;
  }
}

// ---------------------------------------------------------------- final combine (deterministic)
__global__ __launch_bounds__(256)
void combine_kernel(const float* __restrict__ xres, const ushort* __restrict__ eo,
                    const int* __restrict__ inv, const float* __restrict__ ew,
                    float* __restrict__ outx, float* __restrict__ aux) {
  int token = blockIdx.x;
  int d = threadIdx.x * 4;
  float4 acc = *(const float4*)&xres[(size_t)token * 1024 + d];
  #pragma unroll
  for (int j = 0; j < 2; ++j) {
    int p = inv[token * 2 + j];
    if (p >= 0) {
      float w = ew[p];
      const ushort* ep = eo + (size_t)p * 1024 + d;
      acc.x += w * bf2f(ep[0]); acc.y += w * bf2f(ep[1]);
      acc.z += w * bf2f(ep[2]); acc.w += w * bf2f(ep[3]);
    }
  }
  *(float4*)&outx[(size_t)token * 1024 + d] = acc;
  if (token == 0 && threadIdx.x == 0) aux[0] = 0.0f;
}

// ================================================================ launch
extern "C" void kernel_launch(void* const* d_in, const int* in_sizes, int n_in,
                              void* d_out, int out_size, void* d_ws, size_t ws_size,
                              hipStream_t stream) {
  const float* x     = (const float*)d_in[0];
  const float* ln1g  = (const float*)d_in[1];
  const float* ln1b  = (const float*)d_in[2];
  const float* ln2g  = (const float*)d_in[3];
  const float* ln2b  = (const float*)d_in[4];
  const float* Wqkv  = (const float*)d_in[5];
  const float* Wproj = (const float*)d_in[6];
  const float* Wg    = (const float*)d_in[7];
  const float* W1    = (const float*)d_in[8];
  const float* b1    = (const float*)d_in[9];
  const float* W2    = (const float*)d_in[10];
  const float* b2    = (const float*)d_in[11];

  float* out_x   = (float*)d_out;
  float* out_aux = out_x + 4194304;
  float* out_k   = out_aux + 1;
  float* out_v   = out_k + 4194304;

  float* ws   = (float*)d_ws;
  float* A    = ws;                          // x_res
  ushort* KhQ = (ushort*)(ws + 4194304);     // [2][16][2048][64] bf16
  ushort* KlQ = KhQ + 4194304;
  ushort* Qh_ = (ushort*)(ws + 16777216);    // [4096][1024] bf16 (pre-scaled Q hi)
  ushort* Ql_ = (ushort*)(ws + 18874368);    // [4096][1024] bf16 (lo)
  float* st   = ws + 20971520;
  float* ct   = ws + 21037056;
  int*   te   = (int*)(ws + 21102592);
  float* tv   = ws + 21110784;
  int*   etok = (int*)(ws + 21118976);
  float* ew   = ws + 21127168;
  int*   inv  = (int*)(ws + 21135360);
  ushort* bfAh = (ushort*)(ws + 21143552);   // [4096][1024] bf16
  ushort* bfAl = (ushort*)(ws + 23240704);
  ushort* BqH  = (ushort*)(ws + 25337856);   // WqkvT hi [3072][1024]
  ushort* BqL  = (ushort*)(ws + 26910720);
  ushort* BpH  = (ushort*)(ws + 28483584);   // WprojT hi [1024][1024]
  ushort* BpL  = (ushort*)(ws + 29007872);
  ushort* W1t  = (ushort*)(ws + 29532160);   // [8][4096][1024] (written AFTER fmerge)
  ushort* W2t  = (ushort*)(ws + 46309376);   // [8][1024][4096] (written AFTER fmerge)
  ushort* eo   = (ushort*)(ws + 63086592);   // [8192][1024] bf16
  ushort* hbuf = (ushort*)(ws + 4194304);    // [8][1024][4096] bf16 — reuses KhQ/KlQ
                                             // region AFTER flash/fmerge are done
  ushort* Vth_ = eo;                         // [2][16][64][2048]
  ushort* Vtl_ = eo + 4194304;
  float* Opart = ws + 29532160;              // [1280][128][64] (aliases W1t until fmerge)
  float* Mpart = ws + 40017920;              // [1280][128]
  float* Lpart = ws + 40181760;              // [1280][128]

  // weight prep needed before flash (W1/W2 transposes after fmerge)
  tconv4L_kernel<<<dim3(48, 16, 1), 256, 0, stream>>>(Wqkv,  BqH, BqL, 1024, 3072);
  tconv4L_kernel<<<dim3(16, 16, 1), 256, 0, stream>>>(Wproj, BpH, BpL, 1024, 1024);
  sincos_kernel<<<TT, 32, 0, stream>>>(st, ct);

  // LN1 (fused bf16 split)
  ln_kernel<false><<<NTOK, 256, 0, stream>>>(x, ln1g, ln1b, bfAh, bfAl,
                                             nullptr, nullptr, nullptr, nullptr);
  // QKV with fused RoPE epilogue: writes Qh/Ql, KhQ/KlQ, out_k, out_v directly.
  mgemm<4, false, true><<<dim3(24, 32, 1), 256, 0, stream>>>(
      bfAh, bfAl, BqH, BqL, nullptr, nullptr, nullptr, 3072, 1024, 0, 0, 0, 0,
      st, ct, out_k, out_v, KhQ, KlQ, Qh_, Ql_);
  vtprep_kernel<<<dim3(32, 16, 2), 256, 0, stream>>>(out_v, Vth_, Vtl_);
  // split-KV flash + merge (merge writes proj-input splits directly)
  flash11_kernel<<<1280, 256, 0, stream>>>(Qh_, Ql_, KhQ, KlQ, Vth_, Vtl_,
                                           Opart, Mpart, Lpart);
  fmerge2_kernel<<<dim3(16, 32), 256, 0, stream>>>(Opart, Mpart, Lpart, bfAh, bfAl);
  // proj + residual (split-bf16, combined 3-term staging)
  mgemm<1, false, true><<<dim3(8, 32, 1), 256, 0, stream>>>(
      bfAh, bfAl, BpH, BpL, A, x, nullptr, 1024, 1024, 0, 0, 0, 0,
      nullptr, nullptr, nullptr, nullptr, nullptr, nullptr, nullptr, nullptr);
  // expert weight prep, vectorized (W1t/W2t regions free after fmerge)
  tconv4_kernel<<<dim3(64, 16, 8), 256, 0, stream>>>(W1, W1t, 1024, 4096);
  tconv4_kernel<<<dim3(16, 64, 8), 256, 0, stream>>>(W2, W2t, 4096, 1024);
  // LN2 + fused gate (bit-identical summation via LDS row staging)
  ln_kernel<true><<<NTOK, 256, 0, stream>>>(A, ln2g, ln2b, bfAh, bfAl, Wg, te, tv, inv);
  route_sort_kernel<<<8, 1024, 0, stream>>>(te, tv, etok, ew, inv);
  // experts: up (gather + gelu -> bf16 hbuf), down (-> bf16 eo) — r17 reg-staged path
  mgemm<2, true, false><<<dim3(32, 8, 8), 256, 0, stream>>>(
      bfAh, nullptr, W1t, nullptr, hbuf, b1, etok, 4096, 1024,
      0, 4096L * 1024, 1024L * 4096, 4096,
      nullptr, nullptr, nullptr, nullptr, nullptr, nullptr, nullptr, nullptr);
  mgemm<3, false, false><<<dim3(8, 8, 8), 256, 0, stream>>>(
      hbuf, nullptr, W2t, nullptr, eo, b2, nullptr, 1024, 4096,
      1024L * 4096, 1024L * 4096, 1024L * 1024, 1024,
      nullptr, nullptr, nullptr, nullptr, nullptr, nullptr, nullptr, nullptr);
  combine_kernel<<<NTOK, 256, 0, stream>>>(A, eo, inv, ew, out_x, out_aux);
}